// Round 13
// baseline (288.470 us; speedup 1.0000x reference)
//
#include <hip/hip_runtime.h>
#include <math.h>

constexpr int V = 128;   // vocab (fixed for this instance)

// ---- DPP wave-wide shifts (VALU, no LDS pipe, no lgkm wait) ----
__device__ __forceinline__ double dpp_shr1_f64(double x) {
    int lo = __builtin_amdgcn_update_dpp(0, __double2loint(x), 0x138, 0xf, 0xf, false);
    int hi = __builtin_amdgcn_update_dpp(0, __double2hiint(x), 0x138, 0xf, 0xf, false);
    return __hiloint2double(hi, lo);
}
__device__ __forceinline__ double dpp_shl1_f64(double x) {
    int lo = __builtin_amdgcn_update_dpp(0, __double2loint(x), 0x130, 0xf, 0xf, false);
    int hi = __builtin_amdgcn_update_dpp(0, __double2hiint(x), 0x130, 0xf, 0xf, false);
    return __hiloint2double(hi, lo);
}

__device__ __forceinline__ unsigned f32_to_bf16_rne(float f) {
    unsigned u = __float_as_uint(f);
    return (u + 0x7fffu + ((u >> 16) & 1u)) >> 16;
}

// ======================= PATH A ============================================
// MEASURED HISTORY (condensed):
// r17: two-kernel f64 depth-16: scan 81us, total 166 (best verified).
// r18/r19: traffic/depth/memory-path changes: scan invariant at ~81
//   => 190cyc/step structural. Fused overhead = 62us vs 85us two-kernel.
// r20/r21: fused, but shfl-gather producer (ds_bpermute) serializes on the
//   per-CU LDS pipe (conflicts 835K, identical for 1 or 2 gather waves) AND
//   VGPR=68 forced per-row load->use serialization (~20Kcyc/chunk producer
//   vs 6.1K consumer) -> 222/237us. Producer design wrong, skeleton right.
// r22: producers rebuilt on the r8-PROVEN 8-deep register-ring prefetch:
//   - gather waves use SCATTERED GLOBAL loads (rp[la.*], 4 lines/row max,
//     zero LDS-pipe use except conflict-free ring writes);
//   - z-wave same 8-deep ring on full rows;
//   - slot index = j&7 (compile-time after unroll, rule r5);
//   Consumer/ring/rescale/rendezvous byte-identical to r21 (verified).
__global__ __launch_bounds__(256, 1) void ctc_fused_bi(
    const float* __restrict__ pred,
    const int*   __restrict__ pred_len,
    const int*   __restrict__ gt,
    const int*   __restrict__ gt_len,
    double*      __restrict__ fwdv,   // [B,520]
    double*      __restrict__ bwdv,   // [B,520]
    int*         __restrict__ Kf,     // [B]
    int*         __restrict__ Kb,     // [B]
    double*      __restrict__ zpart,  // [2B] per-direction zs partials
    int* done, int* gdone, float* lossb,
    float* __restrict__ out,
    int T, int S, int B)
{
    const int blk  = blockIdx.x;
    const int b    = blk >> 1;
    const int dir  = blk & 1;
    const int wv   = threadIdx.x >> 6;   // 0=consumer 1,3=g-gather 2=z
    const int lane = threadIdx.x & 63;
    const int len  = pred_len[b];     // host guards T>=128 -> len>=64
    const int tl   = gt_len[b];
    const int L    = 2 * tl + 1;
    const int m    = (len + 1) >> 1;  // fwd rows (>=32); nb = len-m >= 32

    __shared__ uint2  ring[2][32][64];   // 32 KB double-buffered g chunks
    __shared__ double zsh;               // wv2 -> wv0 handoff

    int4 la = *(const int4*)(gt + b * S + 4 * lane);
    int law_up = __shfl_up(la.w, 1, 64);     // init-time only: DS ok here
    int lax_dn = __shfl_down(la.x, 1, 64);
    const double sk0 = (lane > 0 && la.x != law_up) ? 1.0 : 0.0; // skip[8i+1]
    const double sk1 = (la.y != la.x) ? 1.0 : 0.0;               // skip[8i+3]
    const double sk2 = (la.z != la.y) ? 1.0 : 0.0;               // skip[8i+5]
    const double sk3 = (la.w != la.z) ? 1.0 : 0.0;               // skip[8i+7]
    const double sk4 = (lax_dn != la.w) ? 1.0 : 0.0;             // skip[8i+9]

    const float2* rowp = (const float2*)(pred + (size_t)b * T * V);
    const float*  rowf = pred + (size_t)b * T * V;

    double u[9];
    int    K  = 0;
    double zs = 0.0;

    auto RESCALE = [&]() {
        double mx = u[0];
        #pragma unroll
        for (int j = 1; j < 9; ++j) mx = fmax(mx, u[j]);
        #pragma unroll
        for (int off = 32; off >= 1; off >>= 1)
            mx = fmax(mx, __shfl_xor(mx, off, 64));
        int k = ((__double2hiint(mx) >> 20) & 0x7ff) - 1023;
        #pragma unroll
        for (int j = 0; j < 9; ++j) u[j] = ldexp(u[j], -k);  // exact
        K += k;
    };

    auto FSTEP_Q = [&](uint2 q) {
        double um1 = dpp_shr1_f64(u[7]);          // lane0 -> 0 (exact)
        double gx = (double)__uint_as_float(q.x << 16);
        double gy = (double)__uint_as_float(q.x & 0xffff0000u);
        double gz = (double)__uint_as_float(q.y << 16);
        double gw = (double)__uint_as_float(q.y & 0xffff0000u);
        u[8] = u[8] + u[7];
        u[7] = (fma(sk3, u[5], u[6]) + u[7]) * gw;
        u[6] = u[6] + u[5];
        u[5] = (fma(sk2, u[3], u[4]) + u[5]) * gz;
        u[4] = u[4] + u[3];
        u[3] = (fma(sk1, u[1], u[2]) + u[3]) * gy;
        u[2] = u[2] + u[1];
        u[1] = (fma(sk0, um1, u[0]) + u[1]) * gx;
        u[0] = u[0] + um1;
    };

    auto BSTEP_Q = [&](uint2 q) {
        double d0 = dpp_shl1_f64(u[0]);           // slot 8i+8 (pre-step)
        if (lane == 63) d0 = u[8];
        double gx = (double)__uint_as_float(q.x << 16);
        double gy = (double)__uint_as_float(q.x & 0xffff0000u);
        double gz = (double)__uint_as_float(q.y << 16);
        double gw = (double)__uint_as_float(q.y & 0xffff0000u);
        double p1 = gx * u[1], p3 = gy * u[3];
        double p5 = gz * u[5], p7 = gw * u[7];
        double dp = dpp_shl1_f64(p1);             // lane63 -> 0
        u[0] = u[0] + p1;
        u[1] = fma(sk1, p3, u[2]) + p1;
        u[2] = u[2] + p3;
        u[3] = fma(sk2, p5, u[4]) + p3;
        u[4] = u[4] + p5;
        u[5] = fma(sk3, p7, u[6]) + p5;
        u[6] = u[6] + p7;
        u[7] = fma(sk4, dp, d0) + p7;
    };

    const int h16 = (wv == 3) ? 16 : 0;   // gather-wave half offset

    // producer register rings (gather waves + z wave)
    float4 gr[8]; float gx0[8];          // gather: 8-deep row ring
    float2 zr[8];                        // z: 8-deep row ring

    if (dir == 0) {
        // ---------------- forward: rows 0..m-1 (row 0 = init) -------------
        #pragma unroll
        for (int j = 0; j < 9; ++j) u[j] = 0.0;
        const int nrows = m;
        const int nch = (nrows + 31) >> 5;

        if (wv == 1 || wv == 3) {        // preload gather ring: chunk0 rows
            #pragma unroll
            for (int j = 0; j < 8; ++j) {
                int r = h16 + j; if (r > len - 1) r = len - 1;
                const float* rp = rowf + (size_t)r * V;
                gx0[j] = rp[0];
                gr[j].x = rp[la.x]; gr[j].y = rp[la.y];
                gr[j].z = rp[la.z]; gr[j].w = rp[la.w];
            }
        }
        if (wv == 2) {                   // preload z ring: rows 0..7
            #pragma unroll
            for (int j = 0; j < 8; ++j)
                zr[j] = rowp[(size_t)j * 64 + lane];
        }

        for (int it = 0; it <= nch; ++it) {
            if ((wv == 1 || wv == 3) && it < nch) {   // produce half-chunk
                int base = (it << 5) + h16, buf = it & 1;
                #pragma unroll
                for (int j = 0; j < 16; ++j) {
                    float4 q = gr[j & 7]; float x0 = gx0[j & 7];
                    int off = (j < 8) ? (j + 8) : (j + 24);  // slot's next row
                    int nr = base + off; if (nr > len - 1) nr = len - 1;
                    const float* rp = rowf + (size_t)nr * V;
                    gx0[j & 7] = rp[0];
                    float4 t;
                    t.x = rp[la.x]; t.y = rp[la.y];
                    t.z = rp[la.z]; t.w = rp[la.w];
                    gr[j & 7] = t;
                    float o0 = (4 * lane + 0 < tl) ? __expf(q.x - x0) : 0.f;
                    float o1 = (4 * lane + 1 < tl) ? __expf(q.y - x0) : 0.f;
                    float o2 = (4 * lane + 2 < tl) ? __expf(q.z - x0) : 0.f;
                    float o3 = (4 * lane + 3 < tl) ? __expf(q.w - x0) : 0.f;
                    uint2 w;
                    w.x = f32_to_bf16_rne(o0) | (f32_to_bf16_rne(o1) << 16);
                    w.y = f32_to_bf16_rne(o2) | (f32_to_bf16_rne(o3) << 16);
                    ring[buf][h16 + j][lane] = w;
                }
            }
            if (wv == 2 && it < nch) {       // z for chunk it's rows
                int base = it << 5;
                #pragma unroll
                for (int j = 0; j < 32; ++j) {
                    float2 v = zr[j & 7];
                    int nr = base + j + 8; if (nr > len - 1) nr = len - 1;
                    zr[j & 7] = rowp[(size_t)nr * 64 + lane];
                    float x0 = __shfl(v.x, 0, 64);
                    float s = __expf(v.x - x0) + __expf(v.y - x0);
                    #pragma unroll
                    for (int off = 32; off >= 1; off >>= 1)
                        s += __shfl_xor(s, off, 64);
                    if (base + j < nrows) zs += (double)__logf(s);
                }
            }
            if (wv == 0 && it >= 1) {        // consume chunk it-1
                int c = it - 1;
                int buf = c & 1;
                uint2 rr[4];
                #pragma unroll
                for (int j = 0; j < 4; ++j) rr[j] = ring[buf][j][lane];
                if (c == 0) {                // init row + 31 steps
                    if (lane == 0) {
                        u[0] = 1.0;
                        u[1] = (double)__uint_as_float(rr[0].x << 16);
                    }
                    rr[0] = ring[buf][4][lane];
                    #pragma unroll
                    for (int i = 1; i < 32; ++i) {
                        uint2 q = rr[i & 3];
                        if (i + 4 < 32) rr[i & 3] = ring[buf][i + 4][lane];
                        FSTEP_Q(q);
                    }
                } else if (((c + 1) << 5) <= nrows) {   // full chunk
                    #pragma unroll
                    for (int i = 0; i < 32; ++i) {
                        uint2 q = rr[i & 3];
                        if (i + 4 < 32) rr[i & 3] = ring[buf][i + 4][lane];
                        FSTEP_Q(q);
                    }
                } else {                                 // tail chunk
                    int rem = nrows - (c << 5);
                    #pragma unroll
                    for (int i = 0; i < 32; ++i) {
                        if (i < rem) {
                            uint2 q = rr[i & 3];
                            if (i + 4 < 32) rr[i & 3] = ring[buf][i + 4][lane];
                            FSTEP_Q(q);
                        }
                    }
                }
                if (c & 1) RESCALE();        // <=64-step spacing
            }
            __syncthreads();
        }
        if (wv == 0) {
            RESCALE();                       // normalize before junction
            double* outv = fwdv + (size_t)b * 520;
            #pragma unroll
            for (int j = 0; j < 8; ++j) outv[8 * lane + j] = u[j];
            if (lane == 63) outv[512] = u[8];
            if (lane == 0)  Kf[b] = K;
        }
    } else {
        // ---------------- backward: k=0..nb-1, row = len-1-k --------------
        const int nb = len - m;              // >= 32
        #pragma unroll
        for (int j = 0; j < 8; ++j) {
            int s = 8 * lane + j;
            u[j] = (s == 2 * tl || s == 2 * tl - 1) ? 1.0 : 0.0;
        }
        u[8] = (lane == 63 && L == 513) ? 1.0 : 0.0;   // slot 512 (lane 63)
        const int nrows = nb;
        const int nch = (nrows + 31) >> 5;

        if (wv == 1 || wv == 3) {        // preload gather ring (mirrored)
            #pragma unroll
            for (int j = 0; j < 8; ++j) {
                int r = len - 1 - (h16 + j); if (r < 0) r = 0;
                const float* rp = rowf + (size_t)r * V;
                gx0[j] = rp[0];
                gr[j].x = rp[la.x]; gr[j].y = rp[la.y];
                gr[j].z = rp[la.z]; gr[j].w = rp[la.w];
            }
        }
        if (wv == 2) {                   // preload z ring (mirrored)
            #pragma unroll
            for (int j = 0; j < 8; ++j) {
                int r = len - 1 - j; if (r < 0) r = 0;
                zr[j] = rowp[(size_t)r * 64 + lane];
            }
        }

        for (int it = 0; it <= nch; ++it) {
            if ((wv == 1 || wv == 3) && it < nch) {
                int base = (it << 5) + h16, buf = it & 1;
                #pragma unroll
                for (int j = 0; j < 16; ++j) {
                    float4 q = gr[j & 7]; float x0 = gx0[j & 7];
                    int off = (j < 8) ? (j + 8) : (j + 24);
                    int nr = len - 1 - (base + off); if (nr < 0) nr = 0;
                    const float* rp = rowf + (size_t)nr * V;
                    gx0[j & 7] = rp[0];
                    float4 t;
                    t.x = rp[la.x]; t.y = rp[la.y];
                    t.z = rp[la.z]; t.w = rp[la.w];
                    gr[j & 7] = t;
                    float o0 = (4 * lane + 0 < tl) ? __expf(q.x - x0) : 0.f;
                    float o1 = (4 * lane + 1 < tl) ? __expf(q.y - x0) : 0.f;
                    float o2 = (4 * lane + 2 < tl) ? __expf(q.z - x0) : 0.f;
                    float o3 = (4 * lane + 3 < tl) ? __expf(q.w - x0) : 0.f;
                    uint2 w;
                    w.x = f32_to_bf16_rne(o0) | (f32_to_bf16_rne(o1) << 16);
                    w.y = f32_to_bf16_rne(o2) | (f32_to_bf16_rne(o3) << 16);
                    ring[buf][h16 + j][lane] = w;
                }
            }
            if (wv == 2 && it < nch) {
                int base = it << 5;
                #pragma unroll
                for (int j = 0; j < 32; ++j) {
                    float2 v = zr[j & 7];
                    int nr = len - 1 - (base + j + 8); if (nr < 0) nr = 0;
                    zr[j & 7] = rowp[(size_t)nr * 64 + lane];
                    float x0 = __shfl(v.x, 0, 64);
                    float s = __expf(v.x - x0) + __expf(v.y - x0);
                    #pragma unroll
                    for (int off = 32; off >= 1; off >>= 1)
                        s += __shfl_xor(s, off, 64);
                    if (base + j < nrows) zs += (double)__logf(s);
                }
            }
            if (wv == 0 && it >= 1) {
                int c = it - 1;
                int buf = c & 1;
                uint2 rr[4];
                #pragma unroll
                for (int j = 0; j < 4; ++j) rr[j] = ring[buf][j][lane];
                if (((c + 1) << 5) <= nrows) {    // full chunk
                    #pragma unroll
                    for (int i = 0; i < 32; ++i) {
                        uint2 q = rr[i & 3];
                        if (i + 4 < 32) rr[i & 3] = ring[buf][i + 4][lane];
                        BSTEP_Q(q);
                    }
                } else {                          // tail chunk
                    int rem = nrows - (c << 5);
                    #pragma unroll
                    for (int i = 0; i < 32; ++i) {
                        if (i < rem) {
                            uint2 q = rr[i & 3];
                            if (i + 4 < 32) rr[i & 3] = ring[buf][i + 4][lane];
                            BSTEP_Q(q);
                        }
                    }
                }
                if (c & 1) RESCALE();
            }
            __syncthreads();
        }
        if (wv == 0) {
            RESCALE();
            double* outv = bwdv + (size_t)b * 520;
            #pragma unroll
            for (int j = 0; j < 8; ++j) outv[8 * lane + j] = u[j];
            if (lane == 63) outv[512] = u[8];
            if (lane == 0)  Kb[b] = K;
        }
    }

    // -------- zs handoff (wv2 -> wv0), then inter-block rendezvous --------
    if (wv == 2 && lane == 0) zsh = zs;
    __syncthreads();
    if (wv != 0) return;                 // producers done (no barriers left)

    if (lane == 0) zpart[blk] = zsh;     // publish this half's zs
    __threadfence();
    int prev = 0;
    if (lane == 0)
        prev = __hip_atomic_fetch_add(&done[b], 1, __ATOMIC_ACQ_REL,
                                      __HIP_MEMORY_SCOPE_AGENT);
    prev = __shfl(prev, 0, 64);
    if (prev == 0) return;               // first arriver: exit immediately
    __threadfence();                     // acquire the other block's stores

    const double* f = fwdv + (size_t)b * 520;
    const double* w = bwdv + (size_t)b * 520;
    double c = 0.0;
    #pragma unroll
    for (int j = 0; j < 8; ++j)
        c = fma(f[8 * lane + j], w[8 * lane + j], c);
    if (lane == 63) c = fma(f[512], w[512], c);
    #pragma unroll
    for (int off = 32; off >= 1; off >>= 1) c += __shfl_xor(c, off, 64);

    if (lane == 0) {
        double zstot = zpart[2 * b] + zpart[2 * b + 1];
        double logp = log(c)
                    + (double)(Kf[b] + Kb[b]) * 0.6931471805599453 - zstot;
        double loss = -logp;
        if (!(loss < 1e10)) loss = 0.0;   // zero_infinity (+inf / NaN)
        if (loss < 0.0)     loss = 0.0;   // CTC loss >= 0: circuit breaker
        lossb[b] = (float)(loss / (double)tl);
        __threadfence();
        int pg = __hip_atomic_fetch_add(gdone, 1, __ATOMIC_ACQ_REL,
                                        __HIP_MEMORY_SCOPE_AGENT);
        if (pg == B - 1) {                // last batch: deterministic mean
            __threadfence();
            float ssum = 0.0f;
            for (int i = 0; i < B; ++i) ssum += lossb[i];
            out[0] = ssum / (float)B;
        }
    }
}

// ======================= PATH B (fallback: proven round-3) ==================
constexpr int SPL  = 9;
constexpr int RING = 32;

__global__ void ctc_reduce_kernel(const float* __restrict__ ls,
                                  float* __restrict__ out, int B)
{
    if (blockIdx.x == 0 && threadIdx.x == 0) {
        float s = 0.0f;
        for (int i = 0; i < B; ++i) s += ls[i];
        out[0] = s / (float)B;
    }
}

__global__ __launch_bounds__(256) void softmax_z_kernel(
    const float* __restrict__ pred, float* __restrict__ z, int nrows)
{
    int w    = blockIdx.x * 4 + (threadIdx.x >> 6);
    int lane = threadIdx.x & 63;
    if (w >= nrows) return;
    const float2* p = (const float2*)pred;
    float2 v = p[(size_t)w * 64 + lane];
    float s = __expf(v.x) + __expf(v.y);
    #pragma unroll
    for (int off = 32; off >= 1; off >>= 1) s += __shfl_xor(s, off, 64);
    if (lane == 0) z[w] = __logf(s);
}

__device__ __forceinline__ void ctc_step_fb(
    const float* __restrict__ rowbase, const int* __restrict__ goff,
    const double* __restrict__ skd, double (&u)[SPL], int lane)
{
    float gf[SPL];
    #pragma unroll
    for (int j = 0; j < SPL; ++j)
        gf[j] = *(const float*)((const char*)rowbase + goff[j]);
    double um1 = __shfl_up(u[8], 1, 64);
    double um2 = __shfl_up(u[7], 1, 64);
    if (lane == 0) { um1 = 0.0; um2 = 0.0; }
    #pragma unroll
    for (int jj = 0; jj < SPL; ++jj) {
        int j = SPL - 1 - jj;
        double a2 = (j >= 1) ? u[j - 1] : um1;
        double a3 = (j >= 2) ? u[j - 2] : ((j == 1) ? um1 : um2);
        double t  = fma(skd[j], a3, a2) + u[j];
        u[j] = t * (double)gf[j];
    }
}

__device__ __forceinline__ void ctc_rescale_fb(double (&u)[SPL], int& K)
{
    double m = u[0];
    #pragma unroll
    for (int j = 1; j < SPL; ++j) m = fmax(m, u[j]);
    #pragma unroll
    for (int off = 32; off >= 1; off >>= 1) m = fmax(m, __shfl_xor(m, off, 64));
    if (m > 0.0) {
        int e = (__double2hiint(m) >> 20) & 0x7ff;
        int k = e - 1023;
        #pragma unroll
        for (int j = 0; j < SPL; ++j) u[j] = ldexp(u[j], -k);
        K += k;
    }
}

__global__ __launch_bounds__(64) void ctc_scan_kernel(
    const float* __restrict__ pred, const int* __restrict__ pred_len,
    const int* __restrict__ gt, const int* __restrict__ gt_len,
    const float* __restrict__ z, float* __restrict__ loss_out, int T, int S)
{
    const int b    = blockIdx.x;
    const int lane = threadIdx.x;
    const int len  = pred_len[b];
    const int tl   = gt_len[b];
    const int L    = 2 * tl + 1;

    __shared__ float ring[RING][V];
    __shared__ int   gts[512];

    for (int i = lane; i < S; i += 64) gts[i] = gt[b * S + i];
    __syncthreads();

    int    goff[SPL];
    double skd[SPL];
    #pragma unroll
    for (int j = 0; j < SPL; ++j) {
        int s = SPL * lane + j;
        int e = 0, ep = 0;
        if (s < L && (s & 1)) e = gts[s >> 1];
        if (s >= 2 && s < L && (s & 1)) ep = gts[(s - 2) >> 1];
        goff[j] = e * 4;
        skd[j]  = (s >= 2 && s < L && e != 0 && e != ep) ? 1.0 : 0.0;
    }

    const float2* rowp = (const float2*)(pred + (size_t)b * T * V);
    float2 raw[16];

    #pragma unroll
    for (int i = 0; i < 16; ++i) raw[i] = rowp[(size_t)i * 64 + lane];
    #pragma unroll
    for (int i = 0; i < 16; ++i) {
        float2 w; w.x = __expf(raw[i].x); w.y = __expf(raw[i].y);
        *(float2*)&ring[i][2 * lane] = w;
    }
    #pragma unroll
    for (int i = 0; i < 16; ++i) raw[i] = rowp[(size_t)(16 + i) * 64 + lane];
    #pragma unroll
    for (int i = 0; i < 16; ++i) {
        float2 w; w.x = __expf(raw[i].x); w.y = __expf(raw[i].y);
        *(float2*)&ring[16 + i][2 * lane] = w;
    }
    #pragma unroll
    for (int i = 0; i < 16; ++i) {
        int r = 32 + i; if (r > T - 1) r = T - 1;
        raw[i] = rowp[(size_t)r * 64 + lane];
    }

    double u[SPL];
    #pragma unroll
    for (int j = 0; j < SPL; ++j) {
        int s = SPL * lane + j;
        float w0 = *(const float*)((const char*)&ring[0][0] + goff[j]);
        u[j] = (s < 2) ? (double)w0 : 0.0;
    }
    int K = 0;

    for (int t = 1; t < 16 && t < len; ++t)
        ctc_step_fb(&ring[t & (RING - 1)][0], goff, skd, u, lane);
    ctc_rescale_fb(u, K);

    int tb = 16;
    for (; tb + 16 <= len; tb += 16) {
        #pragma unroll
        for (int i = 0; i < 16; ++i) {
            float2 w; w.x = __expf(raw[i].x); w.y = __expf(raw[i].y);
            *(float2*)&ring[(tb + 16 + i) & (RING - 1)][2 * lane] = w;
        }
        #pragma unroll
        for (int i = 0; i < 16; ++i) {
            int r = tb + 32 + i; if (r > T - 1) r = T - 1;
            raw[i] = rowp[(size_t)r * 64 + lane];
        }
        #pragma unroll
        for (int i = 0; i < 16; ++i)
            ctc_step_fb(&ring[(tb + i) & (RING - 1)][0], goff, skd, u, lane);
        ctc_rescale_fb(u, K);
    }

    for (int t = tb; t < len; ++t)
        ctc_step_fb(&ring[t & (RING - 1)][0], goff, skd, u, lane);

    double contrib = 0.0;
    #pragma unroll
    for (int j = 0; j < SPL; ++j) {
        int s = SPL * lane + j;
        if (s == L - 1 || s == L - 2) contrib += u[j];
    }
    #pragma unroll
    for (int off = 32; off >= 1; off >>= 1)
        contrib += __shfl_xor(contrib, off, 64);

    double zsum = 0.0;
    for (int t = lane; t < len; t += 64) zsum += (double)z[b * T + t];
    #pragma unroll
    for (int off = 32; off >= 1; off >>= 1)
        zsum += __shfl_xor(zsum, off, 64);

    if (lane == 0) {
        double lg    = log(contrib);
        double alpha = lg + (double)K * 0.6931471805599453 - zsum;
        double loss  = -alpha;
        if (!(loss < 1e10)) loss = 0.0;
        loss_out[b] = (float)(loss / (double)tl);
    }
}

// ======================= host =======================
extern "C" void kernel_launch(void* const* d_in, const int* in_sizes, int n_in,
                              void* d_out, int out_size, void* d_ws, size_t ws_size,
                              hipStream_t stream) {
    const float* pred = (const float*)d_in[0];   // [B, T, V] fp32
    const int*   plen = (const int*)d_in[1];     // [B]
    const int*   gts  = (const int*)d_in[2];     // [B, S]
    const int*   glen = (const int*)d_in[3];     // [B]

    const int B = in_sizes[1];
    const int S = in_sizes[2] / B;
    const int T = in_sizes[0] / (B * V);
    const size_t BT = (size_t)B * T;

    float* out = (float*)d_out;
    char*  ws  = (char*)d_ws;

    // fast-path workspace layout (tiny now: no g/z intermediates)
    size_t off_fl = 0;                               // done[64]@0 gdone@256 lossb@512
    size_t off_zp = 1024;                            // zpart: 2B doubles
    size_t off_fw = 2048;
    size_t off_bw = off_fw + (size_t)B * 520 * 8;
    size_t off_kf = off_bw + (size_t)B * 520 * 8;
    size_t off_kb = off_kf + (size_t)B * 4;
    size_t need   = off_kb + (size_t)B * 4;

    // T >= 128 (=> len >= 64 => m,nb >= 32) required by 32-row chunking
    bool fast_ok = (ws_size >= need) && (S == 256) &&
                   (T >= 128) && (B >= 1) && (B <= 64);

    if (fast_ok) {
        int*    flags = (int*)(ws + off_fl);
        int*    done  = flags;
        int*    gdone = flags + 64;
        float*  lossb = (float*)(ws + off_fl + 512);
        double* zp    = (double*)(ws + off_zp);
        double* fw    = (double*)(ws + off_fw);
        double* bw    = (double*)(ws + off_bw);
        int*    kf    = (int*)(ws + off_kf);
        int*    kb    = (int*)(ws + off_kb);

        hipMemsetAsync(ws + off_fl, 0, 512, stream);   // done + gdone
        ctc_fused_bi<<<2 * B, 256, 0, stream>>>(pred, plen, gts, glen,
                                                fw, bw, kf, kb, zp,
                                                done, gdone, lossb, out,
                                                T, S, B);
    } else {
        float* zbuf = (float*)ws;                 // B*T
        float* lb   = zbuf + BT;                  // B
        int nrows = B * T;
        softmax_z_kernel<<<(nrows + 3) / 4, 256, 0, stream>>>(pred, zbuf, nrows);
        ctc_scan_kernel<<<B, 64, 0, stream>>>(pred, plen, gts, glen, zbuf, lb, T, S);
        ctc_reduce_kernel<<<1, 64, 0, stream>>>(lb, out, B);
    }
}

// Round 14
// 224.589 us; speedup vs baseline: 1.2844x; 1.2844x over previous
//
#include <hip/hip_runtime.h>
#include <math.h>

constexpr int V = 128;   // vocab (fixed for this instance)

// ---- DPP wave-wide shifts (VALU, no LDS pipe, no lgkm wait) ----
__device__ __forceinline__ double dpp_shr1_f64(double x) {
    int lo = __builtin_amdgcn_update_dpp(0, __double2loint(x), 0x138, 0xf, 0xf, false);
    int hi = __builtin_amdgcn_update_dpp(0, __double2hiint(x), 0x138, 0xf, 0xf, false);
    return __hiloint2double(hi, lo);
}
__device__ __forceinline__ double dpp_shl1_f64(double x) {
    int lo = __builtin_amdgcn_update_dpp(0, __double2loint(x), 0x130, 0xf, 0xf, false);
    int hi = __builtin_amdgcn_update_dpp(0, __double2hiint(x), 0x130, 0xf, 0xf, false);
    return __hiloint2double(hi, lo);
}

__device__ __forceinline__ unsigned f32_to_bf16_rne(float f) {
    unsigned u = __float_as_uint(f);
    return (u + 0x7fffu + ((u >> 16) & 1u)) >> 16;
}

// ======================= PATH A ============================================
// MEASURED HISTORY (condensed):
// r17: two-kernel f64 depth-16: scan 81us, total 166 (best verified).
// r18/r19: scan invariant at ~81 under traffic/depth/memory-path changes
//   => 190cyc/step structural. Fused fixed-overhead 62us vs two-kernel 85.
// r20/r21: fused w/ bpermute gather: LDS-pipe serialization (835K confl).
// r22: scattered-global gather, conflicts -> 0, STILL 226us: (a) gather
//   ring depth 8 covers ~500cyc << ~1000cyc HBM -> ~400cyc stall/iter;
//   (b) z-wave per-row butterfly = serial 280cyc DS chain x32 rows.
//   Producers ~2-3x consumer chunk time -> barrier-gated.
// r23: (a) gather rings 16-deep: next-chunk loads issued a FULL chunk
//   (+barrier) before consumption -> coverage >> HBM latency;
//   (b) z-wave: 16-deep row ring + 8-row batches with INTERLEAVED
//   butterflies (8 independent DS chains, ILP hides latency).
//   Consumer/ring/rescale/rendezvous byte-identical to r20-r22 (verified).
__global__ __launch_bounds__(256, 1) void ctc_fused_bi(
    const float* __restrict__ pred,
    const int*   __restrict__ pred_len,
    const int*   __restrict__ gt,
    const int*   __restrict__ gt_len,
    double*      __restrict__ fwdv,   // [B,520]
    double*      __restrict__ bwdv,   // [B,520]
    int*         __restrict__ Kf,     // [B]
    int*         __restrict__ Kb,     // [B]
    double*      __restrict__ zpart,  // [2B] per-direction zs partials
    int* done, int* gdone, float* lossb,
    float* __restrict__ out,
    int T, int S, int B)
{
    const int blk  = blockIdx.x;
    const int b    = blk >> 1;
    const int dir  = blk & 1;
    const int wv   = threadIdx.x >> 6;   // 0=consumer 1,3=g-gather 2=z
    const int lane = threadIdx.x & 63;
    const int len  = pred_len[b];     // host guards T>=128 -> len>=64
    const int tl   = gt_len[b];
    const int L    = 2 * tl + 1;
    const int m    = (len + 1) >> 1;  // fwd rows (>=32); nb = len-m >= 32

    __shared__ uint2  ring[2][32][64];   // 32 KB double-buffered g chunks
    __shared__ double zsh;               // wv2 -> wv0 handoff

    int4 la = *(const int4*)(gt + b * S + 4 * lane);
    int law_up = __shfl_up(la.w, 1, 64);     // init-time only: DS ok here
    int lax_dn = __shfl_down(la.x, 1, 64);
    const double sk0 = (lane > 0 && la.x != law_up) ? 1.0 : 0.0; // skip[8i+1]
    const double sk1 = (la.y != la.x) ? 1.0 : 0.0;               // skip[8i+3]
    const double sk2 = (la.z != la.y) ? 1.0 : 0.0;               // skip[8i+5]
    const double sk3 = (la.w != la.z) ? 1.0 : 0.0;               // skip[8i+7]
    const double sk4 = (lax_dn != la.w) ? 1.0 : 0.0;             // skip[8i+9]

    const float2* rowp = (const float2*)(pred + (size_t)b * T * V);
    const float*  rowf = pred + (size_t)b * T * V;

    double u[9];
    int    K  = 0;
    double zs = 0.0;

    auto RESCALE = [&]() {
        double mx = u[0];
        #pragma unroll
        for (int j = 1; j < 9; ++j) mx = fmax(mx, u[j]);
        #pragma unroll
        for (int off = 32; off >= 1; off >>= 1)
            mx = fmax(mx, __shfl_xor(mx, off, 64));
        int k = ((__double2hiint(mx) >> 20) & 0x7ff) - 1023;
        #pragma unroll
        for (int j = 0; j < 9; ++j) u[j] = ldexp(u[j], -k);  // exact
        K += k;
    };

    auto FSTEP_Q = [&](uint2 q) {
        double um1 = dpp_shr1_f64(u[7]);          // lane0 -> 0 (exact)
        double gx = (double)__uint_as_float(q.x << 16);
        double gy = (double)__uint_as_float(q.x & 0xffff0000u);
        double gz = (double)__uint_as_float(q.y << 16);
        double gw = (double)__uint_as_float(q.y & 0xffff0000u);
        u[8] = u[8] + u[7];
        u[7] = (fma(sk3, u[5], u[6]) + u[7]) * gw;
        u[6] = u[6] + u[5];
        u[5] = (fma(sk2, u[3], u[4]) + u[5]) * gz;
        u[4] = u[4] + u[3];
        u[3] = (fma(sk1, u[1], u[2]) + u[3]) * gy;
        u[2] = u[2] + u[1];
        u[1] = (fma(sk0, um1, u[0]) + u[1]) * gx;
        u[0] = u[0] + um1;
    };

    auto BSTEP_Q = [&](uint2 q) {
        double d0 = dpp_shl1_f64(u[0]);           // slot 8i+8 (pre-step)
        if (lane == 63) d0 = u[8];
        double gx = (double)__uint_as_float(q.x << 16);
        double gy = (double)__uint_as_float(q.x & 0xffff0000u);
        double gz = (double)__uint_as_float(q.y << 16);
        double gw = (double)__uint_as_float(q.y & 0xffff0000u);
        double p1 = gx * u[1], p3 = gy * u[3];
        double p5 = gz * u[5], p7 = gw * u[7];
        double dp = dpp_shl1_f64(p1);             // lane63 -> 0
        u[0] = u[0] + p1;
        u[1] = fma(sk1, p3, u[2]) + p1;
        u[2] = u[2] + p3;
        u[3] = fma(sk2, p5, u[4]) + p3;
        u[4] = u[4] + p5;
        u[5] = fma(sk3, p7, u[6]) + p5;
        u[6] = u[6] + p7;
        u[7] = fma(sk4, dp, d0) + p7;
    };

    const int h16 = (wv == 3) ? 16 : 0;   // gather-wave half offset

    // producer register rings
    float4 gr[16]; float gx0[16];        // gather: 16-deep (full chunk ahead)
    float2 zr[16];                       // z: 16-deep row ring

    if (dir == 0) {
        // ---------------- forward: rows 0..m-1 (row 0 = init) -------------
        #pragma unroll
        for (int j = 0; j < 9; ++j) u[j] = 0.0;
        const int nrows = m;
        const int nch = (nrows + 31) >> 5;

        if (wv == 1 || wv == 3) {        // preload gather ring: chunk0 half
            #pragma unroll
            for (int j = 0; j < 16; ++j) {
                int r = h16 + j; if (r > len - 1) r = len - 1;
                const float* rp = rowf + (size_t)r * V;
                gx0[j] = rp[0];
                gr[j].x = rp[la.x]; gr[j].y = rp[la.y];
                gr[j].z = rp[la.z]; gr[j].w = rp[la.w];
            }
        }
        if (wv == 2) {                   // preload z ring: rows 0..15
            #pragma unroll
            for (int j = 0; j < 16; ++j) {
                int r = j; if (r > len - 1) r = len - 1;
                zr[j] = rowp[(size_t)r * 64 + lane];
            }
        }

        for (int it = 0; it <= nch; ++it) {
            if ((wv == 1 || wv == 3) && it < nch) {   // produce half-chunk
                int buf = it & 1;
                int nbase = ((it + 1) << 5) + h16;    // next chunk's rows
                #pragma unroll
                for (int j = 0; j < 16; ++j) {
                    float4 q = gr[j]; float x0 = gx0[j];
                    int nr = nbase + j; if (nr > len - 1) nr = len - 1;
                    const float* rp = rowf + (size_t)nr * V;
                    gx0[j] = rp[0];
                    float4 t;
                    t.x = rp[la.x]; t.y = rp[la.y];
                    t.z = rp[la.z]; t.w = rp[la.w];
                    gr[j] = t;
                    float o0 = (4 * lane + 0 < tl) ? __expf(q.x - x0) : 0.f;
                    float o1 = (4 * lane + 1 < tl) ? __expf(q.y - x0) : 0.f;
                    float o2 = (4 * lane + 2 < tl) ? __expf(q.z - x0) : 0.f;
                    float o3 = (4 * lane + 3 < tl) ? __expf(q.w - x0) : 0.f;
                    uint2 w;
                    w.x = f32_to_bf16_rne(o0) | (f32_to_bf16_rne(o1) << 16);
                    w.y = f32_to_bf16_rne(o2) | (f32_to_bf16_rne(o3) << 16);
                    ring[buf][h16 + j][lane] = w;
                }
            }
            if (wv == 2 && it < nch) {       // z: 4 batches of 8 rows, ILP
                int base = it << 5;
                #pragma unroll
                for (int h = 0; h < 4; ++h) {
                    float s8[8];
                    #pragma unroll
                    for (int j = 0; j < 8; ++j) {
                        int slot = (8 * h + j) & 15;  // base%16==0
                        float2 v = zr[slot];
                        int nr = base + 8 * h + j + 16;
                        if (nr > len - 1) nr = len - 1;
                        zr[slot] = rowp[(size_t)nr * 64 + lane];
                        float x0 = __shfl(v.x, 0, 64);
                        s8[j] = __expf(v.x - x0) + __expf(v.y - x0);
                    }
                    #pragma unroll
                    for (int off = 32; off >= 1; off >>= 1) {
                        #pragma unroll
                        for (int j = 0; j < 8; ++j)
                            s8[j] += __shfl_xor(s8[j], off, 64);
                    }
                    #pragma unroll
                    for (int j = 0; j < 8; ++j)
                        if (base + 8 * h + j < nrows)
                            zs += (double)__logf(s8[j]);
                }
            }
            if (wv == 0 && it >= 1) {        // consume chunk it-1
                int c = it - 1;
                int buf = c & 1;
                uint2 rr[4];
                #pragma unroll
                for (int j = 0; j < 4; ++j) rr[j] = ring[buf][j][lane];
                if (c == 0) {                // init row + 31 steps
                    if (lane == 0) {
                        u[0] = 1.0;
                        u[1] = (double)__uint_as_float(rr[0].x << 16);
                    }
                    rr[0] = ring[buf][4][lane];
                    #pragma unroll
                    for (int i = 1; i < 32; ++i) {
                        uint2 q = rr[i & 3];
                        if (i + 4 < 32) rr[i & 3] = ring[buf][i + 4][lane];
                        FSTEP_Q(q);
                    }
                } else if (((c + 1) << 5) <= nrows) {   // full chunk
                    #pragma unroll
                    for (int i = 0; i < 32; ++i) {
                        uint2 q = rr[i & 3];
                        if (i + 4 < 32) rr[i & 3] = ring[buf][i + 4][lane];
                        FSTEP_Q(q);
                    }
                } else {                                 // tail chunk
                    int rem = nrows - (c << 5);
                    #pragma unroll
                    for (int i = 0; i < 32; ++i) {
                        if (i < rem) {
                            uint2 q = rr[i & 3];
                            if (i + 4 < 32) rr[i & 3] = ring[buf][i + 4][lane];
                            FSTEP_Q(q);
                        }
                    }
                }
                if (c & 1) RESCALE();        // <=64-step spacing
            }
            __syncthreads();
        }
        if (wv == 0) {
            RESCALE();                       // normalize before junction
            double* outv = fwdv + (size_t)b * 520;
            #pragma unroll
            for (int j = 0; j < 8; ++j) outv[8 * lane + j] = u[j];
            if (lane == 63) outv[512] = u[8];
            if (lane == 0)  Kf[b] = K;
        }
    } else {
        // ---------------- backward: k=0..nb-1, row = len-1-k --------------
        const int nb = len - m;              // >= 32
        #pragma unroll
        for (int j = 0; j < 8; ++j) {
            int s = 8 * lane + j;
            u[j] = (s == 2 * tl || s == 2 * tl - 1) ? 1.0 : 0.0;
        }
        u[8] = (lane == 63 && L == 513) ? 1.0 : 0.0;   // slot 512 (lane 63)
        const int nrows = nb;
        const int nch = (nrows + 31) >> 5;

        if (wv == 1 || wv == 3) {        // preload gather ring (mirrored)
            #pragma unroll
            for (int j = 0; j < 16; ++j) {
                int r = len - 1 - (h16 + j); if (r < 0) r = 0;
                const float* rp = rowf + (size_t)r * V;
                gx0[j] = rp[0];
                gr[j].x = rp[la.x]; gr[j].y = rp[la.y];
                gr[j].z = rp[la.z]; gr[j].w = rp[la.w];
            }
        }
        if (wv == 2) {                   // preload z ring (mirrored)
            #pragma unroll
            for (int j = 0; j < 16; ++j) {
                int r = len - 1 - j; if (r < 0) r = 0;
                zr[j] = rowp[(size_t)r * 64 + lane];
            }
        }

        for (int it = 0; it <= nch; ++it) {
            if ((wv == 1 || wv == 3) && it < nch) {
                int buf = it & 1;
                int nbase = ((it + 1) << 5) + h16;
                #pragma unroll
                for (int j = 0; j < 16; ++j) {
                    float4 q = gr[j]; float x0 = gx0[j];
                    int nr = len - 1 - (nbase + j); if (nr < 0) nr = 0;
                    const float* rp = rowf + (size_t)nr * V;
                    gx0[j] = rp[0];
                    float4 t;
                    t.x = rp[la.x]; t.y = rp[la.y];
                    t.z = rp[la.z]; t.w = rp[la.w];
                    gr[j] = t;
                    float o0 = (4 * lane + 0 < tl) ? __expf(q.x - x0) : 0.f;
                    float o1 = (4 * lane + 1 < tl) ? __expf(q.y - x0) : 0.f;
                    float o2 = (4 * lane + 2 < tl) ? __expf(q.z - x0) : 0.f;
                    float o3 = (4 * lane + 3 < tl) ? __expf(q.w - x0) : 0.f;
                    uint2 w;
                    w.x = f32_to_bf16_rne(o0) | (f32_to_bf16_rne(o1) << 16);
                    w.y = f32_to_bf16_rne(o2) | (f32_to_bf16_rne(o3) << 16);
                    ring[buf][h16 + j][lane] = w;
                }
            }
            if (wv == 2 && it < nch) {
                int base = it << 5;
                #pragma unroll
                for (int h = 0; h < 4; ++h) {
                    float s8[8];
                    #pragma unroll
                    for (int j = 0; j < 8; ++j) {
                        int slot = (8 * h + j) & 15;
                        float2 v = zr[slot];
                        int nr = len - 1 - (base + 8 * h + j + 16);
                        if (nr < 0) nr = 0;
                        zr[slot] = rowp[(size_t)nr * 64 + lane];
                        float x0 = __shfl(v.x, 0, 64);
                        s8[j] = __expf(v.x - x0) + __expf(v.y - x0);
                    }
                    #pragma unroll
                    for (int off = 32; off >= 1; off >>= 1) {
                        #pragma unroll
                        for (int j = 0; j < 8; ++j)
                            s8[j] += __shfl_xor(s8[j], off, 64);
                    }
                    #pragma unroll
                    for (int j = 0; j < 8; ++j)
                        if (base + 8 * h + j < nrows)
                            zs += (double)__logf(s8[j]);
                }
            }
            if (wv == 0 && it >= 1) {
                int c = it - 1;
                int buf = c & 1;
                uint2 rr[4];
                #pragma unroll
                for (int j = 0; j < 4; ++j) rr[j] = ring[buf][j][lane];
                if (((c + 1) << 5) <= nrows) {    // full chunk
                    #pragma unroll
                    for (int i = 0; i < 32; ++i) {
                        uint2 q = rr[i & 3];
                        if (i + 4 < 32) rr[i & 3] = ring[buf][i + 4][lane];
                        BSTEP_Q(q);
                    }
                } else {                          // tail chunk
                    int rem = nrows - (c << 5);
                    #pragma unroll
                    for (int i = 0; i < 32; ++i) {
                        if (i < rem) {
                            uint2 q = rr[i & 3];
                            if (i + 4 < 32) rr[i & 3] = ring[buf][i + 4][lane];
                            BSTEP_Q(q);
                        }
                    }
                }
                if (c & 1) RESCALE();
            }
            __syncthreads();
        }
        if (wv == 0) {
            RESCALE();
            double* outv = bwdv + (size_t)b * 520;
            #pragma unroll
            for (int j = 0; j < 8; ++j) outv[8 * lane + j] = u[j];
            if (lane == 63) outv[512] = u[8];
            if (lane == 0)  Kb[b] = K;
        }
    }

    // -------- zs handoff (wv2 -> wv0), then inter-block rendezvous --------
    if (wv == 2 && lane == 0) zsh = zs;
    __syncthreads();
    if (wv != 0) return;                 // producers done (no barriers left)

    if (lane == 0) zpart[blk] = zsh;     // publish this half's zs
    __threadfence();
    int prev = 0;
    if (lane == 0)
        prev = __hip_atomic_fetch_add(&done[b], 1, __ATOMIC_ACQ_REL,
                                      __HIP_MEMORY_SCOPE_AGENT);
    prev = __shfl(prev, 0, 64);
    if (prev == 0) return;               // first arriver: exit immediately
    __threadfence();                     // acquire the other block's stores

    const double* f = fwdv + (size_t)b * 520;
    const double* w = bwdv + (size_t)b * 520;
    double c = 0.0;
    #pragma unroll
    for (int j = 0; j < 8; ++j)
        c = fma(f[8 * lane + j], w[8 * lane + j], c);
    if (lane == 63) c = fma(f[512], w[512], c);
    #pragma unroll
    for (int off = 32; off >= 1; off >>= 1) c += __shfl_xor(c, off, 64);

    if (lane == 0) {
        double zstot = zpart[2 * b] + zpart[2 * b + 1];
        double logp = log(c)
                    + (double)(Kf[b] + Kb[b]) * 0.6931471805599453 - zstot;
        double loss = -logp;
        if (!(loss < 1e10)) loss = 0.0;   // zero_infinity (+inf / NaN)
        if (loss < 0.0)     loss = 0.0;   // CTC loss >= 0: circuit breaker
        lossb[b] = (float)(loss / (double)tl);
        __threadfence();
        int pg = __hip_atomic_fetch_add(gdone, 1, __ATOMIC_ACQ_REL,
                                        __HIP_MEMORY_SCOPE_AGENT);
        if (pg == B - 1) {                // last batch: deterministic mean
            __threadfence();
            float ssum = 0.0f;
            for (int i = 0; i < B; ++i) ssum += lossb[i];
            out[0] = ssum / (float)B;
        }
    }
}

// ======================= PATH B (fallback: proven round-3) ==================
constexpr int SPL  = 9;
constexpr int RING = 32;

__global__ void ctc_reduce_kernel(const float* __restrict__ ls,
                                  float* __restrict__ out, int B)
{
    if (blockIdx.x == 0 && threadIdx.x == 0) {
        float s = 0.0f;
        for (int i = 0; i < B; ++i) s += ls[i];
        out[0] = s / (float)B;
    }
}

__global__ __launch_bounds__(256) void softmax_z_kernel(
    const float* __restrict__ pred, float* __restrict__ z, int nrows)
{
    int w    = blockIdx.x * 4 + (threadIdx.x >> 6);
    int lane = threadIdx.x & 63;
    if (w >= nrows) return;
    const float2* p = (const float2*)pred;
    float2 v = p[(size_t)w * 64 + lane];
    float s = __expf(v.x) + __expf(v.y);
    #pragma unroll
    for (int off = 32; off >= 1; off >>= 1) s += __shfl_xor(s, off, 64);
    if (lane == 0) z[w] = __logf(s);
}

__device__ __forceinline__ void ctc_step_fb(
    const float* __restrict__ rowbase, const int* __restrict__ goff,
    const double* __restrict__ skd, double (&u)[SPL], int lane)
{
    float gf[SPL];
    #pragma unroll
    for (int j = 0; j < SPL; ++j)
        gf[j] = *(const float*)((const char*)rowbase + goff[j]);
    double um1 = __shfl_up(u[8], 1, 64);
    double um2 = __shfl_up(u[7], 1, 64);
    if (lane == 0) { um1 = 0.0; um2 = 0.0; }
    #pragma unroll
    for (int jj = 0; jj < SPL; ++jj) {
        int j = SPL - 1 - jj;
        double a2 = (j >= 1) ? u[j - 1] : um1;
        double a3 = (j >= 2) ? u[j - 2] : ((j == 1) ? um1 : um2);
        double t  = fma(skd[j], a3, a2) + u[j];
        u[j] = t * (double)gf[j];
    }
}

__device__ __forceinline__ void ctc_rescale_fb(double (&u)[SPL], int& K)
{
    double m = u[0];
    #pragma unroll
    for (int j = 1; j < SPL; ++j) m = fmax(m, u[j]);
    #pragma unroll
    for (int off = 32; off >= 1; off >>= 1) m = fmax(m, __shfl_xor(m, off, 64));
    if (m > 0.0) {
        int e = (__double2hiint(m) >> 20) & 0x7ff;
        int k = e - 1023;
        #pragma unroll
        for (int j = 0; j < SPL; ++j) u[j] = ldexp(u[j], -k);
        K += k;
    }
}

__global__ __launch_bounds__(64) void ctc_scan_kernel(
    const float* __restrict__ pred, const int* __restrict__ pred_len,
    const int* __restrict__ gt, const int* __restrict__ gt_len,
    const float* __restrict__ z, float* __restrict__ loss_out, int T, int S)
{
    const int b    = blockIdx.x;
    const int lane = threadIdx.x;
    const int len  = pred_len[b];
    const int tl   = gt_len[b];
    const int L    = 2 * tl + 1;

    __shared__ float ring[RING][V];
    __shared__ int   gts[512];

    for (int i = lane; i < S; i += 64) gts[i] = gt[b * S + i];
    __syncthreads();

    int    goff[SPL];
    double skd[SPL];
    #pragma unroll
    for (int j = 0; j < SPL; ++j) {
        int s = SPL * lane + j;
        int e = 0, ep = 0;
        if (s < L && (s & 1)) e = gts[s >> 1];
        if (s >= 2 && s < L && (s & 1)) ep = gts[(s - 2) >> 1];
        goff[j] = e * 4;
        skd[j]  = (s >= 2 && s < L && e != 0 && e != ep) ? 1.0 : 0.0;
    }

    const float2* rowp = (const float2*)(pred + (size_t)b * T * V);
    float2 raw[16];

    #pragma unroll
    for (int i = 0; i < 16; ++i) raw[i] = rowp[(size_t)i * 64 + lane];
    #pragma unroll
    for (int i = 0; i < 16; ++i) {
        float2 w; w.x = __expf(raw[i].x); w.y = __expf(raw[i].y);
        *(float2*)&ring[i][2 * lane] = w;
    }
    #pragma unroll
    for (int i = 0; i < 16; ++i) raw[i] = rowp[(size_t)(16 + i) * 64 + lane];
    #pragma unroll
    for (int i = 0; i < 16; ++i) {
        float2 w; w.x = __expf(raw[i].x); w.y = __expf(raw[i].y);
        *(float2*)&ring[16 + i][2 * lane] = w;
    }
    #pragma unroll
    for (int i = 0; i < 16; ++i) {
        int r = 32 + i; if (r > T - 1) r = T - 1;
        raw[i] = rowp[(size_t)r * 64 + lane];
    }

    double u[SPL];
    #pragma unroll
    for (int j = 0; j < SPL; ++j) {
        int s = SPL * lane + j;
        float w0 = *(const float*)((const char*)&ring[0][0] + goff[j]);
        u[j] = (s < 2) ? (double)w0 : 0.0;
    }
    int K = 0;

    for (int t = 1; t < 16 && t < len; ++t)
        ctc_step_fb(&ring[t & (RING - 1)][0], goff, skd, u, lane);
    ctc_rescale_fb(u, K);

    int tb = 16;
    for (; tb + 16 <= len; tb += 16) {
        #pragma unroll
        for (int i = 0; i < 16; ++i) {
            float2 w; w.x = __expf(raw[i].x); w.y = __expf(raw[i].y);
            *(float2*)&ring[(tb + 16 + i) & (RING - 1)][2 * lane] = w;
        }
        #pragma unroll
        for (int i = 0; i < 16; ++i) {
            int r = tb + 32 + i; if (r > T - 1) r = T - 1;
            raw[i] = rowp[(size_t)r * 64 + lane];
        }
        #pragma unroll
        for (int i = 0; i < 16; ++i)
            ctc_step_fb(&ring[(tb + i) & (RING - 1)][0], goff, skd, u, lane);
        ctc_rescale_fb(u, K);
    }

    for (int t = tb; t < len; ++t)
        ctc_step_fb(&ring[t & (RING - 1)][0], goff, skd, u, lane);

    double contrib = 0.0;
    #pragma unroll
    for (int j = 0; j < SPL; ++j) {
        int s = SPL * lane + j;
        if (s == L - 1 || s == L - 2) contrib += u[j];
    }
    #pragma unroll
    for (int off = 32; off >= 1; off >>= 1)
        contrib += __shfl_xor(contrib, off, 64);

    double zsum = 0.0;
    for (int t = lane; t < len; t += 64) zsum += (double)z[b * T + t];
    #pragma unroll
    for (int off = 32; off >= 1; off >>= 1)
        zsum += __shfl_xor(zsum, off, 64);

    if (lane == 0) {
        double lg    = log(contrib);
        double alpha = lg + (double)K * 0.6931471805599453 - zsum;
        double loss  = -alpha;
        if (!(loss < 1e10)) loss = 0.0;
        loss_out[b] = (float)(loss / (double)tl);
    }
}

// ======================= host =======================
extern "C" void kernel_launch(void* const* d_in, const int* in_sizes, int n_in,
                              void* d_out, int out_size, void* d_ws, size_t ws_size,
                              hipStream_t stream) {
    const float* pred = (const float*)d_in[0];   // [B, T, V] fp32
    const int*   plen = (const int*)d_in[1];     // [B]
    const int*   gts  = (const int*)d_in[2];     // [B, S]
    const int*   glen = (const int*)d_in[3];     // [B]

    const int B = in_sizes[1];
    const int S = in_sizes[2] / B;
    const int T = in_sizes[0] / (B * V);
    const size_t BT = (size_t)B * T;

    float* out = (float*)d_out;
    char*  ws  = (char*)d_ws;

    // fast-path workspace layout (tiny now: no g/z intermediates)
    size_t off_fl = 0;                               // done[64]@0 gdone@256 lossb@512
    size_t off_zp = 1024;                            // zpart: 2B doubles
    size_t off_fw = 2048;
    size_t off_bw = off_fw + (size_t)B * 520 * 8;
    size_t off_kf = off_bw + (size_t)B * 520 * 8;
    size_t off_kb = off_kf + (size_t)B * 4;
    size_t need   = off_kb + (size_t)B * 4;

    // T >= 128 (=> len >= 64 => m,nb >= 32) required by 32-row chunking
    bool fast_ok = (ws_size >= need) && (S == 256) &&
                   (T >= 128) && (B >= 1) && (B <= 64);

    if (fast_ok) {
        int*    flags = (int*)(ws + off_fl);
        int*    done  = flags;
        int*    gdone = flags + 64;
        float*  lossb = (float*)(ws + off_fl + 512);
        double* zp    = (double*)(ws + off_zp);
        double* fw    = (double*)(ws + off_fw);
        double* bw    = (double*)(ws + off_bw);
        int*    kf    = (int*)(ws + off_kf);
        int*    kb    = (int*)(ws + off_kb);

        hipMemsetAsync(ws + off_fl, 0, 512, stream);   // done + gdone
        ctc_fused_bi<<<2 * B, 256, 0, stream>>>(pred, plen, gts, glen,
                                                fw, bw, kf, kb, zp,
                                                done, gdone, lossb, out,
                                                T, S, B);
    } else {
        float* zbuf = (float*)ws;                 // B*T
        float* lb   = zbuf + BT;                  // B
        int nrows = B * T;
        softmax_z_kernel<<<(nrows + 3) / 4, 256, 0, stream>>>(pred, zbuf, nrows);
        ctc_scan_kernel<<<B, 64, 0, stream>>>(pred, plen, gts, glen, zbuf, lb, T, S);
        ctc_reduce_kernel<<<1, 64, 0, stream>>>(lb, out, B);
    }
}

// Round 15
// 166.739 us; speedup vs baseline: 1.7301x; 1.3470x over previous
//
#include <hip/hip_runtime.h>
#include <math.h>

constexpr int V = 128;   // vocab (fixed for this instance)

// ---- DPP wave-wide shifts (VALU, no LDS pipe, no lgkm wait) ----
// "shr1" = receive from lane-1 (ctrl 0x138), "shl1" = receive from lane+1
// (0x130). Validated in the passing f64 r8/r17 kernels.
__device__ __forceinline__ double dpp_shr1_f64(double x) {
    int lo = __builtin_amdgcn_update_dpp(0, __double2loint(x), 0x138, 0xf, 0xf, false);
    int hi = __builtin_amdgcn_update_dpp(0, __double2hiint(x), 0x138, 0xf, 0xf, false);
    return __hiloint2double(hi, lo);
}
__device__ __forceinline__ double dpp_shl1_f64(double x) {
    int lo = __builtin_amdgcn_update_dpp(0, __double2loint(x), 0x130, 0xf, 0xf, false);
    int hi = __builtin_amdgcn_update_dpp(0, __double2hiint(x), 0x130, 0xf, 0xf, false);
    return __hiloint2double(hi, lo);
}

// ======================= PATH A (r17 — best verified: 166.2us) =============
// FINAL MEASURED MAP (14 rounds):
// - Scan floor: 190cyc/step, INVARIANT to {f32/f64 state, depth 16/32,
//   f32/bf16 g, VMEM vs LDS feed} (r10-r19). ~95 issue + ~95 dep/hazard
//   stall; single-wave serial recurrence, wave-packing can't beat it.
// - Fixed part ~85us (launch + prelude + harness). Fusion (r20-r23) moves
//   prelude work from a 16K-block grid (latency hidden by TLP) onto 3
//   waves in 64 blocks (192 CUs idle) -> producers gate the consumer:
//   222/237/226/155us >> 85us consumer. Structurally unfixable; reverted.
// - This file == round-8 kernel that measured 166.2us / absmax 0.0.
__global__ __launch_bounds__(256) void ctc_prelude(
    const float* __restrict__ pred, const int* __restrict__ gt,
    const int* __restrict__ gt_len, const int* __restrict__ pred_len,
    float* __restrict__ g, float* __restrict__ z, int* __restrict__ flags,
    int T, int S)
{
    // fused flag-zeroing (replaces hipMemsetAsync): done[64] + gdone
    if (blockIdx.x == 0 && threadIdx.x < 65) flags[threadIdx.x] = 0;

    int wid  = blockIdx.x * 4 + (threadIdx.x >> 6);
    int lane = threadIdx.x & 63;
    int w4   = threadIdx.x >> 6;
    int b    = wid / T;
    int t    = wid - b * T;
    if (t >= pred_len[b]) return;     // wave-uniform: rows beyond len unread
    __shared__ float rows[4][V];      // wave-private regions: no barrier

    const float2* p = (const float2*)pred + (size_t)wid * 64;
    float2 v = p[lane];
    rows[w4][2 * lane]     = v.x;
    rows[w4][2 * lane + 1] = v.y;
    float x0 = __shfl(v.x, 0, 64);
    float s = __expf(v.x) + __expf(v.y);
    #pragma unroll
    for (int off = 32; off >= 1; off >>= 1) s += __shfl_xor(s, off, 64);
    if (lane == 0) z[wid] = __logf(s) - v.x;   // store z - x0 directly

    int4 la = *(const int4*)(gt + b * S + 4 * lane);
    int tl = gt_len[b];
    float4 o;
    o.x = (4 * lane + 0 < tl) ? __expf(rows[w4][la.x] - x0) : 0.f;
    o.y = (4 * lane + 1 < tl) ? __expf(rows[w4][la.y] - x0) : 0.f;
    o.z = (4 * lane + 2 < tl) ? __expf(rows[w4][la.z] - x0) : 0.f;
    o.w = (4 * lane + 3 < tl) ? __expf(rows[w4][la.w] - x0) : 0.f;
    *(float4*)(g + (size_t)wid * 256 + 4 * lane) = o;
}

// Scan (2B blocks, 1 wave each) + fused no-spin epilogue. f64 state, wave
// rescale every <=64 steps, depth-16 prefetch ring (r8-verified).
__global__ __launch_bounds__(64, 1) void ctc_scan_bi(
    const float* __restrict__ g,
    const int*   __restrict__ pred_len,
    const int*   __restrict__ gt,
    const int*   __restrict__ gt_len,
    const float* __restrict__ z,      // pre-normalized: z_t - x0_t
    double*      __restrict__ fwdv,   // [B,520]
    double*      __restrict__ bwdv,   // [B,520]
    int*         __restrict__ Kf,     // [B]
    int*         __restrict__ Kb,     // [B]
    int* done, int* gdone, float* lossb,
    float* __restrict__ out,
    int T, int S, int B)
{
    const int blk  = blockIdx.x;
    const int b    = blk >> 1;
    const int dir  = blk & 1;
    const int lane = threadIdx.x;
    const int len  = pred_len[b];     // host guards T>=96 -> len>=48
    const int tl   = gt_len[b];
    const int L    = 2 * tl + 1;
    const int m    = (len + 1) >> 1;  // forward frames; backward nb = len-m

    int4 la = *(const int4*)(gt + b * S + 4 * lane);
    int law_up = __shfl_up(la.w, 1, 64);     // init-time only: DS ok here
    int lax_dn = __shfl_down(la.x, 1, 64);
    const double sk0 = (lane > 0 && la.x != law_up) ? 1.0 : 0.0; // skip[8i+1]
    const double sk1 = (la.y != la.x) ? 1.0 : 0.0;               // skip[8i+3]
    const double sk2 = (la.z != la.y) ? 1.0 : 0.0;               // skip[8i+5]
    const double sk3 = (la.w != la.z) ? 1.0 : 0.0;               // skip[8i+7]
    const double sk4 = (lax_dn != la.w) ? 1.0 : 0.0;             // skip[8i+9]

    const char* gb = (const char*)(g + (size_t)b * T * 256) + lane * 16;

    float4 raw[16];                   // depth-16 ring (verified optimum)
    double u[9];
    int K = 0;

    auto RESCALE = [&]() {
        double mx = u[0];
        #pragma unroll
        for (int j = 1; j < 9; ++j) mx = fmax(mx, u[j]);
        #pragma unroll
        for (int off = 32; off >= 1; off >>= 1)
            mx = fmax(mx, __shfl_xor(mx, off, 64));
        int k = ((__double2hiint(mx) >> 20) & 0x7ff) - 1023;
        #pragma unroll
        for (int j = 0; j < 9; ++j) u[j] = ldexp(u[j], -k);  // exact
        K += k;
    };

    if (dir == 0) {
        // ---------------- forward ----------------
        #pragma unroll
        for (int i = 0; i < 16; ++i)
            raw[i] = *(const float4*)(gb + (size_t)i * 1024);
        #pragma unroll
        for (int j = 0; j < 9; ++j) u[j] = 0.0;
        if (lane == 0) { u[0] = 1.0; u[1] = (double)raw[0].x; }
        raw[0] = *(const float4*)(gb + (size_t)16 * 1024);
        const char* pf = gb + (size_t)17 * 1024;

        auto FSTEP = [&](int i) {   // i MUST be compile-time constant (r5)
            float4 g4 = raw[i];
            raw[i] = *(const float4*)pf; pf += 1024;  // issue prefetch early
            double um1 = dpp_shr1_f64(u[7]);          // lane0 -> 0 (exact)
            double gx = (double)g4.x, gy = (double)g4.y;
            double gz = (double)g4.z, gw = (double)g4.w;
            u[8] = u[8] + u[7];
            u[7] = (fma(sk3, u[5], u[6]) + u[7]) * gw;
            u[6] = u[6] + u[5];
            u[5] = (fma(sk2, u[3], u[4]) + u[5]) * gz;
            u[4] = u[4] + u[3];
            u[3] = (fma(sk1, u[1], u[2]) + u[3]) * gy;
            u[2] = u[2] + u[1];
            u[1] = (fma(sk0, um1, u[0]) + u[1]) * gx;
            u[0] = u[0] + um1;
        };

        #pragma unroll
        for (int t = 1; t < 16; ++t) FSTEP(t);
        int tb = 16;
        for (; tb + 16 <= m; tb += 16) {
            #pragma unroll
            for (int i = 0; i < 16; ++i) FSTEP(i);
            if (((tb + 16) & 63) == 0) RESCALE();
        }
        #pragma unroll
        for (int i = 0; i < 15; ++i)
            if (tb + i < m) FSTEP(i);
        RESCALE();   // normalize before junction product

        double* outv = fwdv + (size_t)b * 520;
        #pragma unroll
        for (int j = 0; j < 8; ++j) outv[8 * lane + j] = u[j];
        if (lane == 63) outv[512] = u[8];
        if (lane == 0)  Kf[b] = K;
    } else {
        // ---------------- backward ----------------
        const int nb = len - m;      // >= 23 for len >= 48
        #pragma unroll
        for (int i = 0; i < 16; ++i)
            raw[i] = *(const float4*)(gb + (size_t)(len - 1 - i) * 1024);
        #pragma unroll
        for (int j = 0; j < 8; ++j) {
            int s = 8 * lane + j;
            u[j] = (s == 2 * tl || s == 2 * tl - 1) ? 1.0 : 0.0;
        }
        u[8] = (lane == 63 && L == 513) ? 1.0 : 0.0;   // slot 512 (lane 63)
        const char* pf = gb + (size_t)(len - 17) * 1024;

        auto BSTEP = [&](int i) {   // i MUST be compile-time constant
            float4 g4 = raw[i];
            raw[i] = *(const float4*)pf; pf -= 1024;  // issue prefetch early
            double d0 = dpp_shl1_f64(u[0]);           // slot 8i+8 (pre-step)
            if (lane == 63) d0 = u[8];
            double p1 = (double)g4.x * u[1], p3 = (double)g4.y * u[3];
            double p5 = (double)g4.z * u[5], p7 = (double)g4.w * u[7];
            double dp = dpp_shl1_f64(p1);             // lane63 -> 0
            u[0] = u[0] + p1;
            u[1] = fma(sk1, p3, u[2]) + p1;
            u[2] = u[2] + p3;
            u[3] = fma(sk2, p5, u[4]) + p3;
            u[4] = u[4] + p5;
            u[5] = fma(sk3, p7, u[6]) + p5;
            u[6] = u[6] + p7;
            u[7] = fma(sk4, dp, d0) + p7;
        };

        #pragma unroll
        for (int k = 0; k < 16; ++k) BSTEP(k);
        int kb = 16;
        for (; kb + 16 <= nb; kb += 16) {
            #pragma unroll
            for (int i = 0; i < 16; ++i) BSTEP(i);
            if (((kb + 16) & 63) == 0) RESCALE();
        }
        #pragma unroll
        for (int i = 0; i < 15; ++i)
            if (kb + i < nb) BSTEP(i);
        RESCALE();

        double* outv = bwdv + (size_t)b * 520;
        #pragma unroll
        for (int j = 0; j < 8; ++j) outv[8 * lane + j] = u[j];
        if (lane == 63) outv[512] = u[8];
        if (lane == 0)  Kb[b] = K;
    }

    // -------- no-spin rendezvous: second arriver combines (r9-verified) ----
    __threadfence();
    int prev = 0;
    if (lane == 0)
        prev = __hip_atomic_fetch_add(&done[b], 1, __ATOMIC_ACQ_REL,
                                      __HIP_MEMORY_SCOPE_AGENT);
    prev = __shfl(prev, 0, 64);
    if (prev == 0) return;            // first arriver: exit immediately
    __threadfence();                  // acquire the other block's stores

    const double* f = fwdv + (size_t)b * 520;
    const double* w = bwdv + (size_t)b * 520;
    double c = 0.0;
    #pragma unroll
    for (int j = 0; j < 8; ++j)
        c = fma(f[8 * lane + j], w[8 * lane + j], c);
    if (lane == 63) c = fma(f[512], w[512], c);
    #pragma unroll
    for (int off = 32; off >= 1; off >>= 1) c += __shfl_xor(c, off, 64);

    // zs = sum over t<len of (z_t - x0_t); z is pre-normalized. Unrolled x8
    // so loads issue together (was 32 serial ~600cyc loads = ~8us tail).
    double zs = 0.0;
    const float* zb = z + b * T;
    int t = lane;
    for (; t + 448 < len; t += 512) {
        float a0 = zb[t],       a1 = zb[t + 64],  a2 = zb[t + 128];
        float a3 = zb[t + 192], a4 = zb[t + 256], a5 = zb[t + 320];
        float a6 = zb[t + 384], a7 = zb[t + 448];
        zs += (((double)a0 + a1) + ((double)a2 + a3))
            + (((double)a4 + a5) + ((double)a6 + a7));
    }
    for (; t < len; t += 64) zs += (double)zb[t];
    #pragma unroll
    for (int off = 32; off >= 1; off >>= 1) zs += __shfl_xor(zs, off, 64);

    if (lane == 0) {
        double logp = log(c)
                    + (double)(Kf[b] + Kb[b]) * 0.6931471805599453 - zs;
        double loss = -logp;
        if (!(loss < 1e10)) loss = 0.0;   // zero_infinity (+inf / NaN)
        if (loss < 0.0)     loss = 0.0;   // CTC loss >= 0: circuit breaker
        lossb[b] = (float)(loss / (double)tl);
        __threadfence();
        int pg = __hip_atomic_fetch_add(gdone, 1, __ATOMIC_ACQ_REL,
                                        __HIP_MEMORY_SCOPE_AGENT);
        if (pg == B - 1) {                // last batch: deterministic mean
            __threadfence();
            float ssum = 0.0f;
            for (int i = 0; i < B; ++i) ssum += lossb[i];
            out[0] = ssum / (float)B;
        }
    }
}

// ======================= PATH B (fallback: proven round-3) ==================
constexpr int SPL  = 9;
constexpr int RING = 32;

__global__ void ctc_reduce_kernel(const float* __restrict__ ls,
                                  float* __restrict__ out, int B)
{
    if (blockIdx.x == 0 && threadIdx.x == 0) {
        float s = 0.0f;
        for (int i = 0; i < B; ++i) s += ls[i];
        out[0] = s / (float)B;
    }
}

__global__ __launch_bounds__(256) void softmax_z_kernel(
    const float* __restrict__ pred, float* __restrict__ z, int nrows)
{
    int w    = blockIdx.x * 4 + (threadIdx.x >> 6);
    int lane = threadIdx.x & 63;
    if (w >= nrows) return;
    const float2* p = (const float2*)pred;
    float2 v = p[(size_t)w * 64 + lane];
    float s = __expf(v.x) + __expf(v.y);
    #pragma unroll
    for (int off = 32; off >= 1; off >>= 1) s += __shfl_xor(s, off, 64);
    if (lane == 0) z[w] = __logf(s);
}

__device__ __forceinline__ void ctc_step_fb(
    const float* __restrict__ rowbase, const int* __restrict__ goff,
    const double* __restrict__ skd, double (&u)[SPL], int lane)
{
    float gf[SPL];
    #pragma unroll
    for (int j = 0; j < SPL; ++j)
        gf[j] = *(const float*)((const char*)rowbase + goff[j]);
    double um1 = __shfl_up(u[8], 1, 64);
    double um2 = __shfl_up(u[7], 1, 64);
    if (lane == 0) { um1 = 0.0; um2 = 0.0; }
    #pragma unroll
    for (int jj = 0; jj < SPL; ++jj) {
        int j = SPL - 1 - jj;
        double a2 = (j >= 1) ? u[j - 1] : um1;
        double a3 = (j >= 2) ? u[j - 2] : ((j == 1) ? um1 : um2);
        double t  = fma(skd[j], a3, a2) + u[j];
        u[j] = t * (double)gf[j];
    }
}

__device__ __forceinline__ void ctc_rescale_fb(double (&u)[SPL], int& K)
{
    double m = u[0];
    #pragma unroll
    for (int j = 1; j < SPL; ++j) m = fmax(m, u[j]);
    #pragma unroll
    for (int off = 32; off >= 1; off >>= 1) m = fmax(m, __shfl_xor(m, off, 64));
    if (m > 0.0) {
        int e = (__double2hiint(m) >> 20) & 0x7ff;
        int k = e - 1023;
        #pragma unroll
        for (int j = 0; j < SPL; ++j) u[j] = ldexp(u[j], -k);
        K += k;
    }
}

__global__ __launch_bounds__(64) void ctc_scan_kernel(
    const float* __restrict__ pred, const int* __restrict__ pred_len,
    const int* __restrict__ gt, const int* __restrict__ gt_len,
    const float* __restrict__ z, float* __restrict__ loss_out, int T, int S)
{
    const int b    = blockIdx.x;
    const int lane = threadIdx.x;
    const int len  = pred_len[b];
    const int tl   = gt_len[b];
    const int L    = 2 * tl + 1;

    __shared__ float ring[RING][V];
    __shared__ int   gts[512];

    for (int i = lane; i < S; i += 64) gts[i] = gt[b * S + i];
    __syncthreads();

    int    goff[SPL];
    double skd[SPL];
    #pragma unroll
    for (int j = 0; j < SPL; ++j) {
        int s = SPL * lane + j;
        int e = 0, ep = 0;
        if (s < L && (s & 1)) e = gts[s >> 1];
        if (s >= 2 && s < L && (s & 1)) ep = gts[(s - 2) >> 1];
        goff[j] = e * 4;
        skd[j]  = (s >= 2 && s < L && e != 0 && e != ep) ? 1.0 : 0.0;
    }

    const float2* rowp = (const float2*)(pred + (size_t)b * T * V);
    float2 raw[16];

    #pragma unroll
    for (int i = 0; i < 16; ++i) raw[i] = rowp[(size_t)i * 64 + lane];
    #pragma unroll
    for (int i = 0; i < 16; ++i) {
        float2 w; w.x = __expf(raw[i].x); w.y = __expf(raw[i].y);
        *(float2*)&ring[i][2 * lane] = w;
    }
    #pragma unroll
    for (int i = 0; i < 16; ++i) raw[i] = rowp[(size_t)(16 + i) * 64 + lane];
    #pragma unroll
    for (int i = 0; i < 16; ++i) {
        float2 w; w.x = __expf(raw[i].x); w.y = __expf(raw[i].y);
        *(float2*)&ring[16 + i][2 * lane] = w;
    }
    #pragma unroll
    for (int i = 0; i < 16; ++i) {
        int r = 32 + i; if (r > T - 1) r = T - 1;
        raw[i] = rowp[(size_t)r * 64 + lane];
    }

    double u[SPL];
    #pragma unroll
    for (int j = 0; j < SPL; ++j) {
        int s = SPL * lane + j;
        float w0 = *(const float*)((const char*)&ring[0][0] + goff[j]);
        u[j] = (s < 2) ? (double)w0 : 0.0;
    }
    int K = 0;

    for (int t = 1; t < 16 && t < len; ++t)
        ctc_step_fb(&ring[t & (RING - 1)][0], goff, skd, u, lane);
    ctc_rescale_fb(u, K);

    int tb = 16;
    for (; tb + 16 <= len; tb += 16) {
        #pragma unroll
        for (int i = 0; i < 16; ++i) {
            float2 w; w.x = __expf(raw[i].x); w.y = __expf(raw[i].y);
            *(float2*)&ring[(tb + 16 + i) & (RING - 1)][2 * lane] = w;
        }
        #pragma unroll
        for (int i = 0; i < 16; ++i) {
            int r = tb + 32 + i; if (r > T - 1) r = T - 1;
            raw[i] = rowp[(size_t)r * 64 + lane];
        }
        #pragma unroll
        for (int i = 0; i < 16; ++i)
            ctc_step_fb(&ring[(tb + i) & (RING - 1)][0], goff, skd, u, lane);
        ctc_rescale_fb(u, K);
    }

    for (int t = tb; t < len; ++t)
        ctc_step_fb(&ring[t & (RING - 1)][0], goff, skd, u, lane);

    double contrib = 0.0;
    #pragma unroll
    for (int j = 0; j < SPL; ++j) {
        int s = SPL * lane + j;
        if (s == L - 1 || s == L - 2) contrib += u[j];
    }
    #pragma unroll
    for (int off = 32; off >= 1; off >>= 1)
        contrib += __shfl_xor(contrib, off, 64);

    double zsum = 0.0;
    for (int t = lane; t < len; t += 64) zsum += (double)z[b * T + t];
    #pragma unroll
    for (int off = 32; off >= 1; off >>= 1)
        zsum += __shfl_xor(zsum, off, 64);

    if (lane == 0) {
        double lg    = log(contrib);
        double alpha = lg + (double)K * 0.6931471805599453 - zsum;
        double loss  = -alpha;
        if (!(loss < 1e10)) loss = 0.0;
        loss_out[b] = (float)(loss / (double)tl);
    }
}

// ======================= host =======================
extern "C" void kernel_launch(void* const* d_in, const int* in_sizes, int n_in,
                              void* d_out, int out_size, void* d_ws, size_t ws_size,
                              hipStream_t stream) {
    const float* pred = (const float*)d_in[0];   // [B, T, V] fp32
    const int*   plen = (const int*)d_in[1];     // [B]
    const int*   gts  = (const int*)d_in[2];     // [B, S]
    const int*   glen = (const int*)d_in[3];     // [B]

    const int B = in_sizes[1];
    const int S = in_sizes[2] / B;
    const int T = in_sizes[0] / (B * V);
    const size_t BT = (size_t)B * T;

    float* out = (float*)d_out;
    char*  ws  = (char*)d_ws;

    // fast-path workspace layout (8-aligned by construction)
    size_t off_fl  = 0;                              // flags: 1024 B
    size_t off_z   = 1024;
    size_t off_fw  = (off_z + BT * 4 + 255) & ~(size_t)255;
    size_t off_bw  = off_fw  + (size_t)B * 520 * 8;  // f64 junction vectors
    size_t off_kf  = off_bw  + (size_t)B * 520 * 8;
    size_t off_kb  = off_kf  + (size_t)B * 4;
    size_t off_g   = (off_kb + (size_t)B * 4 + 1023) & ~(size_t)1023;
    size_t need    = off_g + BT * 256 * 4;

    bool fast_ok = (ws_size >= need) && (S == 256) && (T % 4 == 0) &&
                   (T >= 96) && (B >= 1) && (B <= 64);

    if (fast_ok) {
        int*    flags = (int*)(ws + off_fl);          // done[64] + gdone
        int*    done  = flags;
        int*    gdone = flags + 64;
        float*  lossb = (float*)(ws + off_fl + 512);  // [64]
        float*  zp    = (float*)(ws + off_z);
        double* fw    = (double*)(ws + off_fw);
        double* bw    = (double*)(ws + off_bw);
        int*    kf    = (int*)(ws + off_kf);
        int*    kb    = (int*)(ws + off_kb);
        float*  g     = (float*)(ws + off_g);

        ctc_prelude<<<B * T / 4, 256, 0, stream>>>(pred, gts, glen, plen,
                                                   g, zp, flags, T, S);
        ctc_scan_bi<<<2 * B, 64, 0, stream>>>(g, plen, gts, glen, zp,
                                              fw, bw, kf, kb,
                                              done, gdone, lossb, out, T, S, B);
    } else {
        float* zbuf = (float*)ws;                 // B*T
        float* lb   = zbuf + BT;                  // B
        int nrows = B * T;
        softmax_z_kernel<<<(nrows + 3) / 4, 256, 0, stream>>>(pred, zbuf, nrows);
        ctc_scan_kernel<<<B, 64, 0, stream>>>(pred, plen, gts, glen, zbuf, lb, T, S);
        ctc_reduce_kernel<<<1, 64, 0, stream>>>(lb, out, B);
    }
}